// Round 1
// baseline (6353.030 us; speedup 1.0000x reference)
//
#include <hip/hip_runtime.h>
#include <stdint.h>

#define TLEN 512
#define HDIM 512
#define DDIM 128
#define NCLS 10

typedef float f32x4 __attribute__((ext_vector_type(4)));
typedef short bf16x8 __attribute__((ext_vector_type(8)));

__device__ __forceinline__ unsigned short f2bf(float f) {
  union { float f; unsigned u; } v; v.f = f;
  return (unsigned short)((v.u + 0x7FFFu + ((v.u >> 16) & 1u)) >> 16);
}
__device__ __forceinline__ float sigm(float x) {
  return __builtin_amdgcn_rcpf(1.0f + __expf(-x));
}

// ---------------- gate tables: G[g][v][h], g in {f,i,c(pre-sigmoided),o} ----
__global__ void k_gates(const float* __restrict__ emb,
                        const float* __restrict__ Wfx, const float* __restrict__ bf_,
                        const float* __restrict__ Wix, const float* __restrict__ bi_,
                        const float* __restrict__ Wcx, const float* __restrict__ bc_,
                        const float* __restrict__ Wox, const float* __restrict__ bo_,
                        float* __restrict__ G) {
  int tid = blockIdx.x * 256 + threadIdx.x;          // 0..6143
  int h = tid & (HDIM - 1);
  int v = (tid >> 9) % 3;
  int g = tid / (3 * HDIM);
  const float* W; const float* bb;
  if (g == 0)      { W = Wfx; bb = bf_; }
  else if (g == 1) { W = Wix; bb = bi_; }
  else if (g == 2) { W = Wcx; bb = bc_; }
  else             { W = Wox; bb = bo_; }
  const float* e = emb + v * DDIM;
  const float* w = W + h * DDIM;
  float s = bb[h];
  #pragma unroll 8
  for (int d = 0; d < DDIM; ++d) s += e[d] * w[d];
  if (g == 2) s = sigm(s);                           // pre-sigmoid the c-gate
  G[tid] = s;
}

// ---------------- weight pack: B-fragments for mfma_f32_16x16x32_bf16 -------
// layout: [wave(8)][kt(16)][gate(2)][nt(4)][lane(64)][e(8)] bf16  (f,i fused)
__global__ void k_pack_fi(const float* __restrict__ Wfh, const float* __restrict__ Wih,
                          unsigned short* __restrict__ pk) {
  int tid = blockIdx.x * 256 + threadIdx.x;          // 0..65535
  int l = tid & 63; int q = tid >> 6;
  int nt = q & 3;  q >>= 2;
  int g  = q & 1;  q >>= 1;
  int kt = q & 15; q >>= 4;
  int w  = q;                                        // 0..7
  int n  = w * 64 + nt * 16 + (l & 15);
  int k0 = kt * 32 + (l >> 4) * 8;
  const float* src = (g ? Wih : Wfh) + n * HDIM + k0;
  unsigned short* dst = pk + (size_t)tid * 8;
  #pragma unroll
  for (int e = 0; e < 8; ++e) dst[e] = f2bf(src[e]);
}

// layout: [wave(8)][kt(16)][nt(4)][lane(64)][e(8)] bf16
__global__ void k_pack_o(const float* __restrict__ Woh, unsigned short* __restrict__ pk) {
  int tid = blockIdx.x * 256 + threadIdx.x;          // 0..32767
  int l = tid & 63; int q = tid >> 6;
  int nt = q & 3;  q >>= 2;
  int kt = q & 15; q >>= 4;
  int w  = q;
  int n  = w * 64 + nt * 16 + (l & 15);
  int k0 = kt * 32 + (l >> 4) * 8;
  const float* src = Woh + n * HDIM + k0;
  unsigned short* dst = pk + (size_t)tid * 8;
  #pragma unroll
  for (int e = 0; e < 8; ++e) dst[e] = f2bf(src[e]);
}

// ---------------- the scan: 16 wgs x 512 thr; wg owns 16 batch rows ---------
__global__ __launch_bounds__(512, 1)
void k_scan(const int* __restrict__ x, const float* __restrict__ G,
            const unsigned short* __restrict__ pk_fi,
            const unsigned short* __restrict__ pk_o,
            float* __restrict__ hfin) {
  __shared__ float Gt[4 * 3 * HDIM];                 // 24 KB
  __shared__ unsigned char xv[16][TLEN];             // 8 KB
  __shared__ unsigned short cb[16][520];             // bf16 c-tile, padded pitch (16B-aligned, bank-spread)

  const int tid  = threadIdx.x;
  const int wg   = blockIdx.x;                       // 0..15
  const int lane = tid & 63;
  const int wave = tid >> 6;                         // 0..7 -> h-slice [wave*64, wave*64+64)

  for (int j = tid; j < 4 * 3 * HDIM; j += 512) Gt[j] = G[j];
  for (int j = tid; j < 16 * TLEN; j += 512) {
    int r = j >> 9, t = j & (TLEN - 1);
    xv[r][t] = (unsigned char)x[(wg * 16 + r) * TLEN + t];
  }
  for (int j = tid; j < 16 * 520; j += 512) ((unsigned short*)cb)[j] = 0;
  __syncthreads();

  float cf[4][4];                                    // fp32 c state: [nt][reg]
  #pragma unroll
  for (int a = 0; a < 4; ++a)
    #pragma unroll
    for (int b = 0; b < 4; ++b) cf[a][b] = 0.f;

  const int rgrp = (lane >> 4) * 4;                  // C/D row base
  const int coll = lane & 15;                        // C/D col (within 16-tile)
  const unsigned short* aptr = &cb[coll][(lane >> 4) * 8];
  const bf16x8* bbase = (const bf16x8*)pk_fi + (size_t)wave * (16 * 2 * 4 * 64) + lane;
  const int hb = wave * 64;
  const f32x4 zz = {0.f, 0.f, 0.f, 0.f};

  for (int t = 0; t < TLEN - 1; ++t) {
    f32x4 af[4], ai[4];
    #pragma unroll
    for (int nt = 0; nt < 4; ++nt) { af[nt] = zz; ai[nt] = zz; }

    #pragma unroll 2
    for (int kt = 0; kt < 16; ++kt) {
      bf16x8 a = *(const bf16x8*)(aptr + kt * 32);   // ds_read_b128
      const bf16x8* bp = bbase + kt * 512;           // contiguous dwordx4 stream
      bf16x8 b0 = bp[0],   b1 = bp[64],  b2 = bp[128], b3 = bp[192];
      bf16x8 b4 = bp[256], b5 = bp[320], b6 = bp[384], b7 = bp[448];
      af[0] = __builtin_amdgcn_mfma_f32_16x16x32_bf16(a, b0, af[0], 0, 0, 0);
      af[1] = __builtin_amdgcn_mfma_f32_16x16x32_bf16(a, b1, af[1], 0, 0, 0);
      af[2] = __builtin_amdgcn_mfma_f32_16x16x32_bf16(a, b2, af[2], 0, 0, 0);
      af[3] = __builtin_amdgcn_mfma_f32_16x16x32_bf16(a, b3, af[3], 0, 0, 0);
      ai[0] = __builtin_amdgcn_mfma_f32_16x16x32_bf16(a, b4, ai[0], 0, 0, 0);
      ai[1] = __builtin_amdgcn_mfma_f32_16x16x32_bf16(a, b5, ai[1], 0, 0, 0);
      ai[2] = __builtin_amdgcn_mfma_f32_16x16x32_bf16(a, b6, ai[2], 0, 0, 0);
      ai[3] = __builtin_amdgcn_mfma_f32_16x16x32_bf16(a, b7, ai[3], 0, 0, 0);
    }
    __syncthreads();                                 // all reads of cb done

    int vv[4];
    #pragma unroll
    for (int r = 0; r < 4; ++r) vv[r] = xv[rgrp + r][t];
    #pragma unroll
    for (int nt = 0; nt < 4; ++nt) {
      const int hcol = hb + nt * 16 + coll;
      #pragma unroll
      for (int r = 0; r < 4; ++r) {
        const float fg = sigm(af[nt][r] + Gt[0 * 1536 + vv[r] * 512 + hcol]);
        const float ig = sigm(ai[nt][r] + Gt[1 * 1536 + vv[r] * 512 + hcol]);
        const float sc = Gt[2 * 1536 + vv[r] * 512 + hcol]; // sigmoid(gc)
        const float cn = sc * ig + cf[nt][r] * fg;
        cf[nt][r] = cn;
        cb[rgrp + r][hcol] = f2bf(cn);
      }
    }
    __syncthreads();                                 // new cb visible
  }

  // ---- final step t = 511: also the o gate, then h = tanh(c)*o -------------
  {
    const int t = TLEN - 1;
    f32x4 af[4], ai[4], ao[4];
    #pragma unroll
    for (int nt = 0; nt < 4; ++nt) { af[nt] = zz; ai[nt] = zz; ao[nt] = zz; }
    const bf16x8* obase = (const bf16x8*)pk_o + (size_t)wave * (16 * 4 * 64) + lane;

    #pragma unroll 2
    for (int kt = 0; kt < 16; ++kt) {
      bf16x8 a = *(const bf16x8*)(aptr + kt * 32);
      const bf16x8* bp = bbase + kt * 512;
      const bf16x8* op = obase + kt * 256;
      bf16x8 b0 = bp[0],   b1 = bp[64],  b2 = bp[128], b3 = bp[192];
      bf16x8 b4 = bp[256], b5 = bp[320], b6 = bp[384], b7 = bp[448];
      bf16x8 o0 = op[0],   o1 = op[64],  o2 = op[128], o3 = op[192];
      af[0] = __builtin_amdgcn_mfma_f32_16x16x32_bf16(a, b0, af[0], 0, 0, 0);
      af[1] = __builtin_amdgcn_mfma_f32_16x16x32_bf16(a, b1, af[1], 0, 0, 0);
      af[2] = __builtin_amdgcn_mfma_f32_16x16x32_bf16(a, b2, af[2], 0, 0, 0);
      af[3] = __builtin_amdgcn_mfma_f32_16x16x32_bf16(a, b3, af[3], 0, 0, 0);
      ai[0] = __builtin_amdgcn_mfma_f32_16x16x32_bf16(a, b4, ai[0], 0, 0, 0);
      ai[1] = __builtin_amdgcn_mfma_f32_16x16x32_bf16(a, b5, ai[1], 0, 0, 0);
      ai[2] = __builtin_amdgcn_mfma_f32_16x16x32_bf16(a, b6, ai[2], 0, 0, 0);
      ai[3] = __builtin_amdgcn_mfma_f32_16x16x32_bf16(a, b7, ai[3], 0, 0, 0);
      ao[0] = __builtin_amdgcn_mfma_f32_16x16x32_bf16(a, o0, ao[0], 0, 0, 0);
      ao[1] = __builtin_amdgcn_mfma_f32_16x16x32_bf16(a, o1, ao[1], 0, 0, 0);
      ao[2] = __builtin_amdgcn_mfma_f32_16x16x32_bf16(a, o2, ao[2], 0, 0, 0);
      ao[3] = __builtin_amdgcn_mfma_f32_16x16x32_bf16(a, o3, ao[3], 0, 0, 0);
    }
    __syncthreads();

    int vv[4];
    #pragma unroll
    for (int r = 0; r < 4; ++r) vv[r] = xv[rgrp + r][t];
    #pragma unroll
    for (int nt = 0; nt < 4; ++nt) {
      const int hcol = hb + nt * 16 + coll;
      #pragma unroll
      for (int r = 0; r < 4; ++r) {
        const float fg = sigm(af[nt][r] + Gt[0 * 1536 + vv[r] * 512 + hcol]);
        const float ig = sigm(ai[nt][r] + Gt[1 * 1536 + vv[r] * 512 + hcol]);
        const float sc = Gt[2 * 1536 + vv[r] * 512 + hcol];
        const float cn = sc * ig + cf[nt][r] * fg;
        const float og = sigm(ao[nt][r] + Gt[3 * 1536 + vv[r] * 512 + hcol]);
        hfin[(wg * 16 + rgrp + r) * HDIM + hcol] = tanhf(cn) * og;
      }
    }
  }
}

// ---------------- classifier head + log_softmax: one wave per row -----------
__global__ __launch_bounds__(64)
void k_head(const float* __restrict__ hfin, const float* __restrict__ Wph,
            const float* __restrict__ bp, float* __restrict__ out) {
  const int b = blockIdx.x;
  const int lane = threadIdx.x;
  float acc[NCLS];
  #pragma unroll
  for (int c = 0; c < NCLS; ++c) acc[c] = 0.f;
  const float* hrow = hfin + b * HDIM;
  for (int k = lane; k < HDIM; k += 64) {
    float hv = hrow[k];
    #pragma unroll
    for (int c = 0; c < NCLS; ++c) acc[c] += hv * Wph[c * HDIM + k];
  }
  #pragma unroll
  for (int c = 0; c < NCLS; ++c)
    #pragma unroll
    for (int off = 32; off > 0; off >>= 1)
      acc[c] += __shfl_down(acc[c], off, 64);
  if (lane == 0) {
    float p[NCLS]; float m = -1e30f;
    #pragma unroll
    for (int c = 0; c < NCLS; ++c) { p[c] = acc[c] + bp[c]; m = fmaxf(m, p[c]); }
    float s = 0.f;
    #pragma unroll
    for (int c = 0; c < NCLS; ++c) s += __expf(p[c] - m);
    const float ls = __logf(s);
    #pragma unroll
    for (int c = 0; c < NCLS; ++c) out[b * NCLS + c] = p[c] - m - ls;
  }
}

extern "C" void kernel_launch(void* const* d_in, const int* in_sizes, int n_in,
                              void* d_out, int out_size, void* d_ws, size_t ws_size,
                              hipStream_t stream) {
  const int*   x   = (const int*)d_in[0];
  const float* emb = (const float*)d_in[1];
  const float* Wfx = (const float*)d_in[2];
  const float* Wfh = (const float*)d_in[3];
  const float* bf_ = (const float*)d_in[4];
  const float* Wix = (const float*)d_in[5];
  const float* Wih = (const float*)d_in[6];
  const float* bi_ = (const float*)d_in[7];
  const float* Wox = (const float*)d_in[8];
  const float* Woh = (const float*)d_in[9];
  const float* bo_ = (const float*)d_in[10];
  const float* Wcx = (const float*)d_in[11];
  const float* bc_ = (const float*)d_in[12];
  const float* Wph = (const float*)d_in[13];
  const float* bp_ = (const float*)d_in[14];

  char* ws = (char*)d_ws;
  float* G              = (float*)(ws);                    // 24 KB
  float* hfin           = (float*)(ws + 32768);            // 512 KB
  unsigned short* pk_fi = (unsigned short*)(ws + 1048576); // 1 MB
  unsigned short* pk_o  = (unsigned short*)(ws + 2097152); // 512 KB

  hipLaunchKernelGGL(k_gates,   dim3(24),  dim3(256), 0, stream,
                     emb, Wfx, bf_, Wix, bi_, Wcx, bc_, Wox, bo_, G);
  hipLaunchKernelGGL(k_pack_fi, dim3(256), dim3(256), 0, stream, Wfh, Wih, pk_fi);
  hipLaunchKernelGGL(k_pack_o,  dim3(128), dim3(256), 0, stream, Woh, pk_o);
  hipLaunchKernelGGL(k_scan,    dim3(16),  dim3(512), 0, stream, x, G, pk_fi, pk_o, hfin);
  hipLaunchKernelGGL(k_head,    dim3(256), dim3(64),  0, stream, hfin, Wph, bp_, (float*)d_out);
}

// Round 2
// 1465.542 us; speedup vs baseline: 4.3349x; 4.3349x over previous
//
#include <hip/hip_runtime.h>
#include <stdint.h>

#define TLEN 512
#define HDIM 512
#define DDIM 128
#define NCLS 10

typedef float f32x4 __attribute__((ext_vector_type(4)));
typedef short bf16x8 __attribute__((ext_vector_type(8)));

__device__ __forceinline__ unsigned short f2bf(float f) {
  union { float f; unsigned u; } v; v.f = f;
  return (unsigned short)((v.u + 0x7FFFu + ((v.u >> 16) & 1u)) >> 16);
}
__device__ __forceinline__ float bf2f(unsigned short h) {
  union { unsigned u; float f; } v; v.u = ((unsigned)h) << 16; return v.f;
}
__device__ __forceinline__ float sigm(float x) {
  return __builtin_amdgcn_rcpf(1.0f + __expf(-x));
}

// ---------------- init: zero the per-tile sync counters ---------------------
__global__ void k_init(int* __restrict__ cnt) {
  if (threadIdx.x < 16) cnt[threadIdx.x] = 0;
}

// ---------------- gate tables: G[g][v][h], g in {f,i,c(pre-sigmoided),o} ----
__global__ void k_gates(const float* __restrict__ emb,
                        const float* __restrict__ Wfx, const float* __restrict__ bf_,
                        const float* __restrict__ Wix, const float* __restrict__ bi_,
                        const float* __restrict__ Wcx, const float* __restrict__ bc_,
                        const float* __restrict__ Wox, const float* __restrict__ bo_,
                        float* __restrict__ G) {
  int tid = blockIdx.x * 256 + threadIdx.x;          // 0..6143
  int h = tid & (HDIM - 1);
  int v = (tid >> 9) % 3;
  int g = tid / (3 * HDIM);
  const float* W; const float* bb;
  if (g == 0)      { W = Wfx; bb = bf_; }
  else if (g == 1) { W = Wix; bb = bi_; }
  else if (g == 2) { W = Wcx; bb = bc_; }
  else             { W = Wox; bb = bo_; }
  const float* e = emb + v * DDIM;
  const float* w = W + h * DDIM;
  float s = bb[h];
  #pragma unroll 8
  for (int d = 0; d < DDIM; ++d) s += e[d] * w[d];
  if (g == 2) s = sigm(s);                           // pre-sigmoid the c-gate
  G[tid] = s;
}

// ---------------- weight pack: register-resident B-fragments ----------------
// pk2: [hs(8)][nt(4)][gate(2)][kt(16)][lane(64)][e(8)] bf16
__global__ void k_pack_fi(const float* __restrict__ Wfh, const float* __restrict__ Wih,
                          unsigned short* __restrict__ pk) {
  int tid = blockIdx.x * 256 + threadIdx.x;          // 0..65535
  int l  = tid & 63;
  int kt = (tid >> 6) & 15;
  int g  = (tid >> 10) & 1;
  int nt = (tid >> 11) & 3;
  int hs = (tid >> 13) & 7;
  int n  = hs * 64 + nt * 16 + (l & 15);
  int k0 = kt * 32 + (l >> 4) * 8;
  const float* src = (g ? Wih : Wfh) + n * HDIM + k0;
  unsigned short* dst = pk + (size_t)tid * 8;
  #pragma unroll
  for (int e = 0; e < 8; ++e) dst[e] = f2bf(src[e]);
}

// pko: [hs(8)][nt(4)][kt(16)][lane(64)][e(8)] bf16
__global__ void k_pack_o(const float* __restrict__ Woh, unsigned short* __restrict__ pk) {
  int tid = blockIdx.x * 256 + threadIdx.x;          // 0..32767
  int l  = tid & 63;
  int kt = (tid >> 6) & 15;
  int nt = (tid >> 10) & 3;
  int hs = (tid >> 12) & 7;
  int n  = hs * 64 + nt * 16 + (l & 15);
  int k0 = kt * 32 + (l >> 4) * 8;
  const float* src = Woh + n * HDIM + k0;
  unsigned short* dst = pk + (size_t)tid * 8;
  #pragma unroll
  for (int e = 0; e < 8; ++e) dst[e] = f2bf(src[e]);
}

// ---------------- scan: 128 WGs = 16 batch-tiles x 8 h-slices ---------------
// Per WG: M=16 rows, N=64 cols, K=512. Weights live in VGPRs for all 512 steps.
// c exchanged per step through LLC with agent-scope stores/loads + counter sync.
__global__ __launch_bounds__(256, 1)
void k_scan(const int* __restrict__ x, const float* __restrict__ G,
            const unsigned short* __restrict__ pk2,
            const unsigned short* __restrict__ pko,
            unsigned int* __restrict__ cbuf, int* __restrict__ cnt,
            unsigned short* __restrict__ hfin) {
  __shared__ float gts[12][68];                      // [g*3+v][col], padded vs 4-way bank alias
  __shared__ unsigned char xv[16][516];              // padded
  __shared__ unsigned short ctile[16][66];           // padded (repack reads)

  const int tid  = threadIdx.x;
  const int lane = tid & 63;
  const int w    = tid >> 6;                         // wave = nt (0..3)
  const int bt   = blockIdx.x & 15;                  // peers (same bt) share XCD mod 8
  const int hs   = blockIdx.x >> 4;

  for (int j = tid; j < 12 * 64; j += 256) {
    int gv = j >> 6, c = j & 63;
    gts[gv][c] = G[gv * HDIM + hs * 64 + c];
  }
  for (int j = tid; j < 16 * TLEN; j += 256) {
    int r = j >> 9, t = j & (TLEN - 1);
    xv[r][t] = (unsigned char)x[(bt * 16 + r) * TLEN + t];
  }

  bf16x8 wf[16], wi[16];
  {
    const bf16x8* ws = (const bf16x8*)pk2 + (size_t)((hs * 4 + w) * 2) * (16 * 64) + lane;
    #pragma unroll
    for (int kt = 0; kt < 16; ++kt) { wf[kt] = ws[kt * 64]; wi[kt] = ws[(16 + kt) * 64]; }
  }

  bf16x8 afr[16];
  #pragma unroll
  for (int kt = 0; kt < 16; ++kt) afr[kt] = bf16x8{0,0,0,0,0,0,0,0};  // c_0 = 0

  float cf[4] = {0.f, 0.f, 0.f, 0.f};
  const int rgrp = (lane >> 4) * 4;
  const int coll = lane & 15;
  const int col  = w * 16 + coll;
  const f32x4 zz = {0.f, 0.f, 0.f, 0.f};
  int* mycnt = cnt + bt;

  __syncthreads();

  for (int t = 0; t < TLEN - 1; ++t) {
    f32x4 af = zz, ai = zz;
    #pragma unroll
    for (int kt = 0; kt < 16; ++kt) {
      af = __builtin_amdgcn_mfma_f32_16x16x32_bf16(afr[kt], wf[kt], af, 0, 0, 0);
      ai = __builtin_amdgcn_mfma_f32_16x16x32_bf16(afr[kt], wi[kt], ai, 0, 0, 0);
    }
    #pragma unroll
    for (int r = 0; r < 4; ++r) {
      int vv = xv[rgrp + r][t];
      float fg = sigm(af[r] + gts[0 + vv][col]);     // g=0 rows 0..2
      float ig = sigm(ai[r] + gts[3 + vv][col]);     // g=1 rows 3..5
      float sc = gts[6 + vv][col];                   // g=2 rows 6..8 (pre-sigmoided)
      float cn = sc * ig + cf[r] * fg;
      cf[r] = cn;
      ctile[rgrp + r][col] = f2bf(cn);
    }
    __syncthreads();                                 // ctile complete

    // repack own slice (kt = 2hs, 2hs+1) into A-frag layout, write-through to LLC
    const unsigned bufo = (unsigned)((((t + 1) & 1) * 16 + bt) * 4096); // dwords
    #pragma unroll
    for (int h2 = 0; h2 < 2; ++h2) {
      int d   = tid + h2 * 256;                      // 0..511
      int ktl = d >> 8, rem = d & 255, lp = rem >> 2, ep = rem & 3;
      int m   = lp & 15;
      int cl  = ktl * 32 + (lp >> 4) * 8 + ep * 2;
      unsigned val = *(const unsigned*)&ctile[m][cl];
      __hip_atomic_store(cbuf + bufo + (unsigned)((hs * 2 + ktl) * 256 + lp * 4 + ep),
                         val, __ATOMIC_RELAXED, __HIP_MEMORY_SCOPE_AGENT);
    }
    __syncthreads();                                 // all stores drained (vmcnt 0)

    if (tid == 0)
      __hip_atomic_fetch_add(mycnt, 1, __ATOMIC_RELAXED, __HIP_MEMORY_SCOPE_AGENT);
    const int target = 8 * (t + 1);
    while (__hip_atomic_load(mycnt, __ATOMIC_RELAXED, __HIP_MEMORY_SCOPE_AGENT) < target)
      __builtin_amdgcn_s_sleep(1);
    asm volatile("" ::: "memory");

    // load fresh A-fragments (c_{t+1}) — agent-scope loads bypass stale L1/L2
    const unsigned long long* ap = (const unsigned long long*)(cbuf + bufo) + (size_t)lane * 2;
    #pragma unroll
    for (int kt = 0; kt < 16; ++kt) {
      unsigned long long lo = __hip_atomic_load(ap + (size_t)kt * 128 + 0,
                                                __ATOMIC_RELAXED, __HIP_MEMORY_SCOPE_AGENT);
      unsigned long long hi = __hip_atomic_load(ap + (size_t)kt * 128 + 1,
                                                __ATOMIC_RELAXED, __HIP_MEMORY_SCOPE_AGENT);
      union { unsigned long long q[2]; bf16x8 v; } u;
      u.q[0] = lo; u.q[1] = hi;
      afr[kt] = u.v;
    }
  }

  // ---- final step t = 511: f, i and o gates; h = tanh(c)*o -----------------
  {
    const int t = TLEN - 1;
    bf16x8 wo[16];
    const bf16x8* os = (const bf16x8*)pko + (size_t)(hs * 4 + w) * (16 * 64) + lane;
    #pragma unroll
    for (int kt = 0; kt < 16; ++kt) wo[kt] = os[kt * 64];
    f32x4 af = zz, ai = zz, ao = zz;
    #pragma unroll
    for (int kt = 0; kt < 16; ++kt) {
      af = __builtin_amdgcn_mfma_f32_16x16x32_bf16(afr[kt], wf[kt], af, 0, 0, 0);
      ai = __builtin_amdgcn_mfma_f32_16x16x32_bf16(afr[kt], wi[kt], ai, 0, 0, 0);
      ao = __builtin_amdgcn_mfma_f32_16x16x32_bf16(afr[kt], wo[kt], ao, 0, 0, 0);
    }
    #pragma unroll
    for (int r = 0; r < 4; ++r) {
      int vv = xv[rgrp + r][t];
      float fg = sigm(af[r] + gts[0 + vv][col]);
      float ig = sigm(ai[r] + gts[3 + vv][col]);
      float sc = gts[6 + vv][col];
      float cn = sc * ig + cf[r] * fg;
      float og = sigm(ao[r] + gts[9 + vv][col]);
      float hv = tanhf(cn) * og;
      hfin[(bt * 16 + rgrp + r) * HDIM + hs * 64 + col] = f2bf(hv);
    }
  }
}

// ---------------- classifier head + log_softmax: one wave per row -----------
__global__ __launch_bounds__(64)
void k_head(const unsigned short* __restrict__ hfin, const float* __restrict__ Wph,
            const float* __restrict__ bp, float* __restrict__ out) {
  const int b = blockIdx.x;
  const int lane = threadIdx.x;
  float acc[NCLS];
  #pragma unroll
  for (int c = 0; c < NCLS; ++c) acc[c] = 0.f;
  const unsigned short* hrow = hfin + (size_t)b * HDIM;
  for (int k = lane; k < HDIM; k += 64) {
    float hv = bf2f(hrow[k]);
    #pragma unroll
    for (int c = 0; c < NCLS; ++c) acc[c] += hv * Wph[c * HDIM + k];
  }
  #pragma unroll
  for (int c = 0; c < NCLS; ++c)
    #pragma unroll
    for (int off = 32; off > 0; off >>= 1)
      acc[c] += __shfl_down(acc[c], off, 64);
  if (lane == 0) {
    float p[NCLS]; float m = -1e30f;
    #pragma unroll
    for (int c = 0; c < NCLS; ++c) { p[c] = acc[c] + bp[c]; m = fmaxf(m, p[c]); }
    float s = 0.f;
    #pragma unroll
    for (int c = 0; c < NCLS; ++c) s += __expf(p[c] - m);
    const float ls = __logf(s);
    #pragma unroll
    for (int c = 0; c < NCLS; ++c) out[b * NCLS + c] = p[c] - m - ls;
  }
}

extern "C" void kernel_launch(void* const* d_in, const int* in_sizes, int n_in,
                              void* d_out, int out_size, void* d_ws, size_t ws_size,
                              hipStream_t stream) {
  const int*   x   = (const int*)d_in[0];
  const float* emb = (const float*)d_in[1];
  const float* Wfx = (const float*)d_in[2];
  const float* Wfh = (const float*)d_in[3];
  const float* bf_ = (const float*)d_in[4];
  const float* Wix = (const float*)d_in[5];
  const float* Wih = (const float*)d_in[6];
  const float* bi_ = (const float*)d_in[7];
  const float* Wox = (const float*)d_in[8];
  const float* Woh = (const float*)d_in[9];
  const float* bo_ = (const float*)d_in[10];
  const float* Wcx = (const float*)d_in[11];
  const float* bc_ = (const float*)d_in[12];
  const float* Wph = (const float*)d_in[13];
  const float* bp_ = (const float*)d_in[14];

  char* ws = (char*)d_ws;
  float*          G    = (float*)(ws);                      // 24 KB  @ 0
  int*            cnt  = (int*)(ws + 24576);                // 64 B   @ 24K
  unsigned short* hfin = (unsigned short*)(ws + 32768);     // 256 KB @ 32K
  unsigned int*   cbuf = (unsigned int*)(ws + 524288);      // 512 KB @ 512K (2 x 16 x 16KB)
  unsigned short* pk2  = (unsigned short*)(ws + 1048576);   // 1 MB   @ 1M
  unsigned short* pko  = (unsigned short*)(ws + 2097152);   // 512 KB @ 2M

  hipLaunchKernelGGL(k_init,    dim3(1),   dim3(64),  0, stream, cnt);
  hipLaunchKernelGGL(k_gates,   dim3(24),  dim3(256), 0, stream,
                     emb, Wfx, bf_, Wix, bi_, Wcx, bc_, Wox, bo_, G);
  hipLaunchKernelGGL(k_pack_fi, dim3(256), dim3(256), 0, stream, Wfh, Wih, pk2);
  hipLaunchKernelGGL(k_pack_o,  dim3(128), dim3(256), 0, stream, Woh, pko);
  hipLaunchKernelGGL(k_scan,    dim3(128), dim3(256), 0, stream, x, G, pk2, pko, cbuf, cnt, hfin);
  hipLaunchKernelGGL(k_head,    dim3(256), dim3(64),  0, stream, hfin, Wph, bp_, (float*)d_out);
}